// Round 1
// baseline (1958.288 us; speedup 1.0000x reference)
//
#include <hip/hip_runtime.h>

namespace {

constexpr int N_NODES = 50000;
constexpr int E_RAW   = 800000;
constexpr int E_TOT   = E_RAW + N_NODES;   // + self loops
constexpr float SLOPE = 0.2f;
constexpr float EPS_V = 1e-16f;

// order-preserving float<->uint mapping for atomicMax on floats
__device__ __forceinline__ unsigned f2o(float f) {
    unsigned u = __float_as_uint(f);
    return (u & 0x80000000u) ? ~u : (u | 0x80000000u);
}
__device__ __forceinline__ float o2f(unsigned m) {
    return __uint_as_float((m & 0x80000000u) ? (m & 0x7fffffffu) : ~m);
}

// ---- GEMM: O[n,0:128] = X[n,0:128] @ W[128,128], fp32 vector ALU ----
// 128-row tile, K split in two 64-wide halves staged in LDS (64KB total).
__global__ __launch_bounds__(256) void gemm128_k(
    const float* __restrict__ X, const float* __restrict__ W,
    float* __restrict__ O, int nrows)
{
    __shared__ float Ws[64][128];    // [k][col]
    __shared__ float XsT[64][128];   // [k][row] (transposed tile)
    const int t  = threadIdx.x;
    const int tx = t & 15;           // col group (8 cols)
    const int ty = t >> 4;           // row group (8 rows)
    const int row0 = blockIdx.x * 128;

    float acc[8][8];
    #pragma unroll
    for (int i = 0; i < 8; ++i)
        #pragma unroll
        for (int j = 0; j < 8; ++j) acc[i][j] = 0.f;

    for (int kh = 0; kh < 2; ++kh) {
        // stage W half: 8192 floats = 2048 float4
        const float4* Wv = (const float4*)(W + (size_t)kh * 64 * 128);
        float4* Wsv = (float4*)&Ws[0][0];
        #pragma unroll
        for (int i = 0; i < 8; ++i) Wsv[t + 256 * i] = Wv[t + 256 * i];
        // stage X half transposed: XsT[k][r] = X[row0+r][kh*64 + k]
        #pragma unroll
        for (int ii = 0; ii < 8; ++ii) {
            int idx = t + 256 * ii;            // 0..2047
            int r   = idx & 127;
            int q   = idx >> 7;                // float4 chunk of k (0..15)
            int gr  = row0 + r;
            float4 v = make_float4(0.f, 0.f, 0.f, 0.f);
            if (gr < nrows) v = *(const float4*)(X + (size_t)gr * 128 + kh * 64 + q * 4);
            XsT[q * 4 + 0][r] = v.x;
            XsT[q * 4 + 1][r] = v.y;
            XsT[q * 4 + 2][r] = v.z;
            XsT[q * 4 + 3][r] = v.w;
        }
        __syncthreads();
        #pragma unroll 4
        for (int k = 0; k < 64; ++k) {
            float4 a0 = *(const float4*)&XsT[k][ty * 8];
            float4 a1 = *(const float4*)&XsT[k][ty * 8 + 4];
            float4 b0 = *(const float4*)&Ws[k][tx * 8];
            float4 b1 = *(const float4*)&Ws[k][tx * 8 + 4];
            float av[8] = {a0.x, a0.y, a0.z, a0.w, a1.x, a1.y, a1.z, a1.w};
            float bv[8] = {b0.x, b0.y, b0.z, b0.w, b1.x, b1.y, b1.z, b1.w};
            #pragma unroll
            for (int i = 0; i < 8; ++i)
                #pragma unroll
                for (int j = 0; j < 8; ++j)
                    acc[i][j] = fmaf(av[i], bv[j], acc[i][j]);
        }
        __syncthreads();
    }
    #pragma unroll
    for (int i = 0; i < 8; ++i) {
        int gr = row0 + ty * 8 + i;
        if (gr < nrows) {
            *(float4*)(O + (size_t)gr * 128 + tx * 8) =
                make_float4(acc[i][0], acc[i][1], acc[i][2], acc[i][3]);
            *(float4*)(O + (size_t)gr * 128 + tx * 8 + 4) =
                make_float4(acc[i][4], acc[i][5], acc[i][6], acc[i][7]);
        }
    }
}

// ---- per-(node,head) attention coefficients s = <h, a_src>, d = <h, a_dst> ----
template<int H>
__global__ __launch_bounds__(256) void attn_sd_k(
    const float* __restrict__ Hh, const float* __restrict__ a_src,
    const float* __restrict__ a_dst, float* __restrict__ sb, float* __restrict__ db)
{
    constexpr int C = 128 / H;
    int idx = blockIdx.x * 256 + threadIdx.x;
    if (idx >= N_NODES * H) return;
    int node = idx / H, h = idx - node * H;
    const float4* base = (const float4*)(Hh + (size_t)node * 128 + h * C);
    const float4* as = (const float4*)(a_src + h * C);
    const float4* ad = (const float4*)(a_dst + h * C);
    float sv = 0.f, dv = 0.f;
    #pragma unroll
    for (int c = 0; c < C / 4; ++c) {
        float4 x = base[c], s4 = as[c], d4 = ad[c];
        sv += x.x * s4.x + x.y * s4.y + x.z * s4.z + x.w * s4.w;
        dv += x.x * d4.x + x.y * d4.y + x.z * d4.z + x.w * d4.w;
    }
    sb[idx] = sv;
    db[idx] = dv;
}

__device__ __forceinline__ void edge_endpoints(const int* __restrict__ ei, int e,
                                               int& src, int& dst)
{
    if (e < E_RAW) { src = ei[e]; dst = ei[E_RAW + e]; }
    else           { src = e - E_RAW; dst = src; }
}

// ---- segment max over destination (uint-mapped atomicMax) ----
template<int H>
__global__ __launch_bounds__(256) void edge_max_k(
    const int* __restrict__ ei, const float* __restrict__ sb,
    const float* __restrict__ db, unsigned* __restrict__ mb)
{
    int e = blockIdx.x * 256 + threadIdx.x;
    if (e >= E_TOT) return;
    int src, dst;
    edge_endpoints(ei, e, src, dst);
    #pragma unroll
    for (int h = 0; h < H; ++h) {
        float v = sb[src * H + h] + db[dst * H + h];
        v = v > 0.f ? v : SLOPE * v;
        atomicMax(&mb[dst * H + h], f2o(v));
    }
}

// ---- exp(e - m[dst]) per edge/head + segment-sum denominator ----
template<int H>
__global__ __launch_bounds__(256) void edge_exp_k(
    const int* __restrict__ ei, const float* __restrict__ sb,
    const float* __restrict__ db, const unsigned* __restrict__ mb,
    float* __restrict__ denb, float* __restrict__ exb)
{
    int e = blockIdx.x * 256 + threadIdx.x;
    if (e >= E_TOT) return;
    int src, dst;
    edge_endpoints(ei, e, src, dst);
    #pragma unroll
    for (int h = 0; h < H; ++h) {
        float v = sb[src * H + h] + db[dst * H + h];
        v = v > 0.f ? v : SLOPE * v;
        float ex = expf(v - o2f(mb[dst * H + h]));
        exb[e * H + h] = ex;
        atomicAdd(&denb[dst * H + h], ex);
    }
}

// ---- weighted aggregation: agg[dst,c] += ex[e,h(c)] * h[src,c] ----
template<int H>
__global__ __launch_bounds__(256) void edge_agg_k(
    const int* __restrict__ ei, const float* __restrict__ exb,
    const float* __restrict__ Hh, float* __restrict__ agg)
{
    constexpr int C = 128 / H;
    long long gid = (long long)blockIdx.x * 256 + threadIdx.x;
    int e = (int)(gid >> 7);
    if (e >= E_TOT) return;
    int c = (int)(gid & 127);
    int src, dst;
    edge_endpoints(ei, e, src, dst);
    float ex = exb[e * H + c / C];
    atomicAdd(&agg[(size_t)dst * 128 + c], ex * Hh[(size_t)src * 128 + c]);
}

// ---- normalize by denom, add bias, optional ReLU ----
template<int H, bool RELU>
__global__ __launch_bounds__(256) void finalize_k(
    const float* __restrict__ agg, const float* __restrict__ denb,
    const float* __restrict__ b, float* __restrict__ outv)
{
    constexpr int C = 128 / H;
    int gid = blockIdx.x * 256 + threadIdx.x;
    if (gid >= N_NODES * 128) return;
    int c = gid & 127;
    int node = gid >> 7;
    int h = c / C;
    float v = agg[gid] / (denb[node * H + h] + EPS_V) + b[c];
    if (RELU) v = fmaxf(v, 0.f);
    outv[gid] = v;
}

template<int H, bool RELU>
void run_layer(const float* xin, const float* Wm, const float* as_, const float* ad_,
               const float* bias, const int* ei,
               float* hbuf, float* aggbuf, float* outv,
               float* sb, float* db, unsigned* mb, float* denb, float* exb,
               hipStream_t stream)
{
    gemm128_k<<<(N_NODES + 127) / 128, 256, 0, stream>>>(xin, Wm, hbuf, N_NODES);
    attn_sd_k<H><<<(N_NODES * H + 255) / 256, 256, 0, stream>>>(hbuf, as_, ad_, sb, db);
    hipMemsetAsync(mb, 0, (size_t)N_NODES * H * 4, stream);     // 0 == mapped -inf
    hipMemsetAsync(denb, 0, (size_t)N_NODES * H * 4, stream);
    hipMemsetAsync(aggbuf, 0, (size_t)N_NODES * 128 * 4, stream);
    edge_max_k<H><<<(E_TOT + 255) / 256, 256, 0, stream>>>(ei, sb, db, mb);
    edge_exp_k<H><<<(E_TOT + 255) / 256, 256, 0, stream>>>(ei, sb, db, mb, denb, exb);
    edge_agg_k<H><<<((long long)E_TOT * 128 + 255) / 256, 256, 0, stream>>>(ei, exb, hbuf, aggbuf);
    finalize_k<H, RELU><<<(N_NODES * 128 + 255) / 256, 256, 0, stream>>>(aggbuf, denb, bias, outv);
}

} // namespace

extern "C" void kernel_launch(void* const* d_in, const int* in_sizes, int n_in,
                              void* d_out, int out_size, void* d_ws, size_t ws_size,
                              hipStream_t stream)
{
    (void)in_sizes; (void)n_in; (void)out_size; (void)ws_size;
    const float* x   = (const float*)d_in[0];
    const int*   ei  = (const int*)d_in[1];
    const float* W0  = (const float*)d_in[2];
    const float* as0 = (const float*)d_in[3];
    const float* ad0 = (const float*)d_in[4];
    const float* b0  = (const float*)d_in[5];
    const float* W1  = (const float*)d_in[6];
    const float* as1 = (const float*)d_in[7];
    const float* ad1 = (const float*)d_in[8];
    const float* b1  = (const float*)d_in[9];
    const float* W2  = (const float*)d_in[10];
    const float* as2 = (const float*)d_in[11];
    const float* ad2 = (const float*)d_in[12];
    const float* b2  = (const float*)d_in[13];
    float* out = (float*)d_out;

    char* p = (char*)d_ws;
    float*    A    = (float*)p;  p += (size_t)N_NODES * 128 * 4;   // h buffer
    float*    B    = (float*)p;  p += (size_t)N_NODES * 128 * 4;   // agg/x buffer
    float*    sb   = (float*)p;  p += (size_t)N_NODES * 4 * 4;
    float*    db   = (float*)p;  p += (size_t)N_NODES * 4 * 4;
    unsigned* mb   = (unsigned*)p; p += (size_t)N_NODES * 4 * 4;
    float*    denb = (float*)p;  p += (size_t)N_NODES * 4 * 4;
    float*    exb  = (float*)p;  p += (size_t)E_TOT * 4 * 4;

    // Layer 0: x -> h(A); agg(B); bias+ReLU in place => B = x1
    run_layer<4, true>(x, W0, as0, ad0, b0, ei, A, B, B, sb, db, mb, denb, exb, stream);
    // Layer 1: B -> h(A); agg(d_out); bias+ReLU in place => out = x2
    run_layer<4, true>(B, W1, as1, ad1, b1, ei, A, out, out, sb, db, mb, denb, exb, stream);
    // Layer 2 (H=1): out -> h(A); agg(B); normalize+bias -> out
    run_layer<1, false>(out, W2, as2, ad2, b2, ei, A, B, out, sb, db, mb, denb, exb, stream);
}

// Round 2
// 563.343 us; speedup vs baseline: 3.4762x; 3.4762x over previous
//
#include <hip/hip_runtime.h>

namespace {

constexpr int N_NODES = 50000;
constexpr int E_RAW   = 800000;
constexpr int E_TOT   = E_RAW + N_NODES;   // + self loops
constexpr float SLOPE = 0.2f;
constexpr float EPS_V = 1e-16f;
constexpr int SCAN_BLOCKS = (N_NODES + 255) / 256;   // 196

// ---- GEMM: O[n,0:128] = X[n,0:128] @ W[128,128], fp32 vector ALU ----
__global__ __launch_bounds__(256) void gemm128_k(
    const float* __restrict__ X, const float* __restrict__ W,
    float* __restrict__ O, int nrows)
{
    __shared__ float Ws[64][128];    // [k][col]
    __shared__ float XsT[64][128];   // [k][row]
    const int t  = threadIdx.x;
    const int tx = t & 15;
    const int ty = t >> 4;
    const int row0 = blockIdx.x * 128;

    float acc[8][8];
    #pragma unroll
    for (int i = 0; i < 8; ++i)
        #pragma unroll
        for (int j = 0; j < 8; ++j) acc[i][j] = 0.f;

    for (int kh = 0; kh < 2; ++kh) {
        const float4* Wv = (const float4*)(W + (size_t)kh * 64 * 128);
        float4* Wsv = (float4*)&Ws[0][0];
        #pragma unroll
        for (int i = 0; i < 8; ++i) Wsv[t + 256 * i] = Wv[t + 256 * i];
        #pragma unroll
        for (int ii = 0; ii < 8; ++ii) {
            int idx = t + 256 * ii;
            int r   = idx & 127;
            int q   = idx >> 7;
            int gr  = row0 + r;
            float4 v = make_float4(0.f, 0.f, 0.f, 0.f);
            if (gr < nrows) v = *(const float4*)(X + (size_t)gr * 128 + kh * 64 + q * 4);
            XsT[q * 4 + 0][r] = v.x;
            XsT[q * 4 + 1][r] = v.y;
            XsT[q * 4 + 2][r] = v.z;
            XsT[q * 4 + 3][r] = v.w;
        }
        __syncthreads();
        #pragma unroll 4
        for (int k = 0; k < 64; ++k) {
            float4 a0 = *(const float4*)&XsT[k][ty * 8];
            float4 a1 = *(const float4*)&XsT[k][ty * 8 + 4];
            float4 b0 = *(const float4*)&Ws[k][tx * 8];
            float4 b1 = *(const float4*)&Ws[k][tx * 8 + 4];
            float av[8] = {a0.x, a0.y, a0.z, a0.w, a1.x, a1.y, a1.z, a1.w};
            float bv[8] = {b0.x, b0.y, b0.z, b0.w, b1.x, b1.y, b1.z, b1.w};
            #pragma unroll
            for (int i = 0; i < 8; ++i)
                #pragma unroll
                for (int j = 0; j < 8; ++j)
                    acc[i][j] = fmaf(av[i], bv[j], acc[i][j]);
        }
        __syncthreads();
    }
    #pragma unroll
    for (int i = 0; i < 8; ++i) {
        int gr = row0 + ty * 8 + i;
        if (gr < nrows) {
            *(float4*)(O + (size_t)gr * 128 + tx * 8) =
                make_float4(acc[i][0], acc[i][1], acc[i][2], acc[i][3]);
            *(float4*)(O + (size_t)gr * 128 + tx * 8 + 4) =
                make_float4(acc[i][4], acc[i][5], acc[i][6], acc[i][7]);
        }
    }
}

// ---- per-(node,head) attention coefficients ----
template<int H>
__global__ __launch_bounds__(256) void attn_sd_k(
    const float* __restrict__ Hh, const float* __restrict__ a_src,
    const float* __restrict__ a_dst, float* __restrict__ sb, float* __restrict__ db)
{
    constexpr int C = 128 / H;
    int idx = blockIdx.x * 256 + threadIdx.x;
    if (idx >= N_NODES * H) return;
    int node = idx / H, h = idx - node * H;
    const float4* base = (const float4*)(Hh + (size_t)node * 128 + h * C);
    const float4* as = (const float4*)(a_src + h * C);
    const float4* ad = (const float4*)(a_dst + h * C);
    float sv = 0.f, dv = 0.f;
    #pragma unroll
    for (int c = 0; c < C / 4; ++c) {
        float4 x = base[c], s4 = as[c], d4 = ad[c];
        sv += x.x * s4.x + x.y * s4.y + x.z * s4.z + x.w * s4.w;
        dv += x.x * d4.x + x.y * d4.y + x.z * d4.z + x.w * d4.w;
    }
    sb[idx] = sv;
    db[idx] = dv;
}

__device__ __forceinline__ void edge_endpoints(const int* __restrict__ ei, int e,
                                               int& src, int& dst)
{
    if (e < E_RAW) { src = ei[e]; dst = ei[E_RAW + e]; }
    else           { src = e - E_RAW; dst = src; }
}

// ============ CSR build (once per call) ============
__global__ __launch_bounds__(256) void csr_count_k(
    const int* __restrict__ ei, int* __restrict__ cnt)
{
    int e = blockIdx.x * 256 + threadIdx.x;
    if (e >= E_TOT) return;
    int src, dst;
    edge_endpoints(ei, e, src, dst);
    atomicAdd(&cnt[dst], 1);
}

__device__ __forceinline__ int block_incl_scan_256(int x, int* wsum) {
    int lane = threadIdx.x & 63, wid = threadIdx.x >> 6;
    #pragma unroll
    for (int off = 1; off < 64; off <<= 1) {
        int y = __shfl_up(x, off, 64);
        if (lane >= off) x += y;
    }
    if (lane == 63) wsum[wid] = x;
    __syncthreads();
    int add = 0;
    #pragma unroll
    for (int w = 0; w < 4; ++w) if (w < wid) add += wsum[w];
    return x + add;
}

// k1: local inclusive scan of cnt chunks -> rp (temp), block totals -> bsum
__global__ __launch_bounds__(256) void scan1_k(
    const int* __restrict__ cnt, int* __restrict__ rp, int* __restrict__ bsum)
{
    __shared__ int wsum[4];
    int i = blockIdx.x * 256 + threadIdx.x;
    int x = (i < N_NODES) ? cnt[i] : 0;
    int incl = block_incl_scan_256(x, wsum);
    if (i < N_NODES) rp[i] = incl;
    if (threadIdx.x == 255) bsum[blockIdx.x] = incl;
}

// k2: exclusive scan of 196 block sums (single block)
__global__ __launch_bounds__(256) void scan2_k(int* __restrict__ bsum)
{
    __shared__ int wsum[4];
    int t = threadIdx.x;
    int x = (t < SCAN_BLOCKS) ? bsum[t] : 0;
    int incl = block_incl_scan_256(x, wsum);
    if (t < SCAN_BLOCKS) bsum[t] = incl - x;   // exclusive
}

// k3: rp[i] = global exclusive prefix; cursor[i] = same
__global__ __launch_bounds__(256) void scan3_k(
    const int* __restrict__ cnt, int* __restrict__ rp,
    const int* __restrict__ bsum, int* __restrict__ cursor)
{
    int i = blockIdx.x * 256 + threadIdx.x;
    if (i < N_NODES) {
        int v = rp[i] + bsum[blockIdx.x] - cnt[i];
        rp[i] = v;
        cursor[i] = v;
    }
    if (i == 0) rp[N_NODES] = E_TOT;
}

__global__ __launch_bounds__(256) void csr_scatter_k(
    const int* __restrict__ ei, int* __restrict__ cursor, int* __restrict__ csr_src)
{
    int e = blockIdx.x * 256 + threadIdx.x;
    if (e >= E_TOT) return;
    int src, dst;
    edge_endpoints(ei, e, src, dst);
    int pos = atomicAdd(&cursor[dst], 1);
    csr_src[pos] = src;
}

// ============ fused per-destination GAT aggregation ============
// one 128-thread block per node; online softmax + weighted accumulate, no atomics
template<int H, bool RELU>
__global__ __launch_bounds__(128) void gat_fused_k(
    const int* __restrict__ rp, const int* __restrict__ csr_src,
    const float* __restrict__ Hh, const float* __restrict__ sb,
    const float* __restrict__ db, const float* __restrict__ bias,
    float* __restrict__ outv)
{
    constexpr int C = 128 / H;
    const int n = blockIdx.x;
    const int c = threadIdx.x;
    const int h = c / C;
    const int beg = rp[n], end = rp[n + 1];
    const float dn = db[n * H + h];

    float m = -3.0e38f, den = 0.f, acc = 0.f;
    for (int i = beg; i < end; ++i) {
        int s = csr_src[i];
        float hv = Hh[(size_t)s * 128 + c];
        float v = sb[s * H + h] + dn;
        v = v > 0.f ? v : SLOPE * v;
        if (v <= m) {
            float p = __expf(v - m);
            den += p;
            acc = fmaf(p, hv, acc);
        } else {
            float scale = __expf(m - v);
            den = fmaf(den, scale, 1.f);
            acc = fmaf(acc, scale, hv);
            m = v;
        }
    }
    float o = acc / (den + EPS_V) + bias[c];
    if (RELU) o = fmaxf(o, 0.f);
    outv[(size_t)n * 128 + c] = o;
}

template<int H, bool RELU>
void run_layer(const float* xin, const float* Wm, const float* as_, const float* ad_,
               const float* bias, const int* rp, const int* csr_src,
               float* hbuf, float* outv, float* sb, float* db, hipStream_t stream)
{
    gemm128_k<<<(N_NODES + 127) / 128, 256, 0, stream>>>(xin, Wm, hbuf, N_NODES);
    attn_sd_k<H><<<(N_NODES * H + 255) / 256, 256, 0, stream>>>(hbuf, as_, ad_, sb, db);
    gat_fused_k<H, RELU><<<N_NODES, 128, 0, stream>>>(rp, csr_src, hbuf, sb, db, bias, outv);
}

} // namespace

extern "C" void kernel_launch(void* const* d_in, const int* in_sizes, int n_in,
                              void* d_out, int out_size, void* d_ws, size_t ws_size,
                              hipStream_t stream)
{
    (void)in_sizes; (void)n_in; (void)out_size; (void)ws_size;
    const float* x   = (const float*)d_in[0];
    const int*   ei  = (const int*)d_in[1];
    const float* W0  = (const float*)d_in[2];
    const float* as0 = (const float*)d_in[3];
    const float* ad0 = (const float*)d_in[4];
    const float* b0  = (const float*)d_in[5];
    const float* W1  = (const float*)d_in[6];
    const float* as1 = (const float*)d_in[7];
    const float* ad1 = (const float*)d_in[8];
    const float* b1  = (const float*)d_in[9];
    const float* W2  = (const float*)d_in[10];
    const float* as2 = (const float*)d_in[11];
    const float* ad2 = (const float*)d_in[12];
    const float* b2  = (const float*)d_in[13];
    float* out = (float*)d_out;

    char* p = (char*)d_ws;
    float* A       = (float*)p;  p += (size_t)N_NODES * 128 * 4;   // h buffer
    float* B       = (float*)p;  p += (size_t)N_NODES * 128 * 4;   // x1 / scratch
    float* sb      = (float*)p;  p += (size_t)N_NODES * 4 * 4;
    float* db      = (float*)p;  p += (size_t)N_NODES * 4 * 4;
    int*   cnt     = (int*)p;    p += (size_t)N_NODES * 4;
    int*   rp      = (int*)p;    p += (size_t)(N_NODES + 1) * 4;
    int*   cursor  = (int*)p;    p += (size_t)N_NODES * 4;
    int*   bsum    = (int*)p;    p += (size_t)SCAN_BLOCKS * 4;
    int*   csr_src = (int*)p;    p += (size_t)E_TOT * 4;

    const int EB = (E_TOT + 255) / 256;

    // ---- CSR build (once; reused by all 3 layers) ----
    hipMemsetAsync(cnt, 0, (size_t)N_NODES * 4, stream);
    csr_count_k<<<EB, 256, 0, stream>>>(ei, cnt);
    scan1_k<<<SCAN_BLOCKS, 256, 0, stream>>>(cnt, rp, bsum);
    scan2_k<<<1, 256, 0, stream>>>(bsum);
    scan3_k<<<SCAN_BLOCKS, 256, 0, stream>>>(cnt, rp, bsum, cursor);
    csr_scatter_k<<<EB, 256, 0, stream>>>(ei, cursor, csr_src);

    // Layer 0: x -> h(A); fused agg -> B (ReLU)
    run_layer<4, true >(x,   W0, as0, ad0, b0, rp, csr_src, A, B,   sb, db, stream);
    // Layer 1: B -> h(A); fused agg -> out (ReLU)
    run_layer<4, true >(B,   W1, as1, ad1, b1, rp, csr_src, A, out, sb, db, stream);
    // Layer 2 (H=1): out -> h(A); fused agg -> out (no ReLU)
    run_layer<1, false>(out, W2, as2, ad2, b2, rp, csr_src, A, out, sb, db, stream);
}

// Round 3
// 420.960 us; speedup vs baseline: 4.6520x; 1.3382x over previous
//
#include <hip/hip_runtime.h>

namespace {

constexpr int N_NODES = 50000;
constexpr int E_RAW   = 800000;
constexpr int E_TOT   = E_RAW + N_NODES;   // + self loops
constexpr float SLOPE = 0.2f;
constexpr float EPS_V = 1e-16f;
constexpr int SCAN_BLOCKS = (N_NODES + 255) / 256;   // 196

// ---- GEMM: O[n,0:128] = X[n,0:128] @ W[128,128] + fused attn s/d epilogue ----
template<int H>
__global__ __launch_bounds__(256) void gemm128_k(
    const float* __restrict__ X, const float* __restrict__ W,
    float* __restrict__ O, int nrows,
    const float* __restrict__ a_src, const float* __restrict__ a_dst,
    float* __restrict__ sb, float* __restrict__ db)
{
    __shared__ float Ws[64][128];    // [k][col]
    __shared__ float XsT[64][128];   // [k][row]
    const int t  = threadIdx.x;
    const int tx = t & 15;
    const int ty = t >> 4;
    const int row0 = blockIdx.x * 128;

    float acc[8][8];
    #pragma unroll
    for (int i = 0; i < 8; ++i)
        #pragma unroll
        for (int j = 0; j < 8; ++j) acc[i][j] = 0.f;

    for (int kh = 0; kh < 2; ++kh) {
        const float4* Wv = (const float4*)(W + (size_t)kh * 64 * 128);
        float4* Wsv = (float4*)&Ws[0][0];
        #pragma unroll
        for (int i = 0; i < 8; ++i) Wsv[t + 256 * i] = Wv[t + 256 * i];
        #pragma unroll
        for (int ii = 0; ii < 8; ++ii) {
            int idx = t + 256 * ii;
            int r   = idx & 127;
            int q   = idx >> 7;
            int gr  = row0 + r;
            float4 v = make_float4(0.f, 0.f, 0.f, 0.f);
            if (gr < nrows) v = *(const float4*)(X + (size_t)gr * 128 + kh * 64 + q * 4);
            XsT[q * 4 + 0][r] = v.x;
            XsT[q * 4 + 1][r] = v.y;
            XsT[q * 4 + 2][r] = v.z;
            XsT[q * 4 + 3][r] = v.w;
        }
        __syncthreads();
        #pragma unroll 4
        for (int k = 0; k < 64; ++k) {
            float4 a0 = *(const float4*)&XsT[k][ty * 8];
            float4 a1 = *(const float4*)&XsT[k][ty * 8 + 4];
            float4 b0 = *(const float4*)&Ws[k][tx * 8];
            float4 b1 = *(const float4*)&Ws[k][tx * 8 + 4];
            float av[8] = {a0.x, a0.y, a0.z, a0.w, a1.x, a1.y, a1.z, a1.w};
            float bv[8] = {b0.x, b0.y, b0.z, b0.w, b1.x, b1.y, b1.z, b1.w};
            #pragma unroll
            for (int i = 0; i < 8; ++i)
                #pragma unroll
                for (int j = 0; j < 8; ++j)
                    acc[i][j] = fmaf(av[i], bv[j], acc[i][j]);
        }
        __syncthreads();
    }
    // store O
    #pragma unroll
    for (int i = 0; i < 8; ++i) {
        int gr = row0 + ty * 8 + i;
        if (gr < nrows) {
            *(float4*)(O + (size_t)gr * 128 + tx * 8) =
                make_float4(acc[i][0], acc[i][1], acc[i][2], acc[i][3]);
            *(float4*)(O + (size_t)gr * 128 + tx * 8 + 4) =
                make_float4(acc[i][4], acc[i][5], acc[i][6], acc[i][7]);
        }
    }
    // fused attn coefficients: s[row,h] = <h_row, a_src[h]>, d likewise
    float as_c[8], ad_c[8];
    #pragma unroll
    for (int j = 0; j < 8; ++j) {
        as_c[j] = a_src[tx * 8 + j];
        ad_c[j] = a_dst[tx * 8 + j];
    }
    #pragma unroll
    for (int i = 0; i < 8; ++i) {
        float sp = 0.f, dp = 0.f;
        #pragma unroll
        for (int j = 0; j < 8; ++j) {
            sp = fmaf(acc[i][j], as_c[j], sp);
            dp = fmaf(acc[i][j], ad_c[j], dp);
        }
        int gr = row0 + ty * 8 + i;
        if (H == 4) {
            sp += __shfl_xor(sp, 1, 64); sp += __shfl_xor(sp, 2, 64);
            dp += __shfl_xor(dp, 1, 64); dp += __shfl_xor(dp, 2, 64);
            if ((tx & 3) == 0 && gr < nrows) {
                sb[gr * 4 + (tx >> 2)] = sp;
                db[gr * 4 + (tx >> 2)] = dp;
            }
        } else {
            sp += __shfl_xor(sp, 1, 64); sp += __shfl_xor(sp, 2, 64);
            sp += __shfl_xor(sp, 4, 64); sp += __shfl_xor(sp, 8, 64);
            dp += __shfl_xor(dp, 1, 64); dp += __shfl_xor(dp, 2, 64);
            dp += __shfl_xor(dp, 4, 64); dp += __shfl_xor(dp, 8, 64);
            if (tx == 0 && gr < nrows) { sb[gr] = sp; db[gr] = dp; }
        }
    }
}

__device__ __forceinline__ void edge_endpoints(const int* __restrict__ ei, int e,
                                               int& src, int& dst)
{
    if (e < E_RAW) { src = ei[e]; dst = ei[E_RAW + e]; }
    else           { src = e - E_RAW; dst = src; }
}

// ============ CSR build (once per call) ============
__global__ __launch_bounds__(256) void csr_count_k(
    const int* __restrict__ ei, int* __restrict__ cnt)
{
    int e = blockIdx.x * 256 + threadIdx.x;
    if (e >= E_TOT) return;
    int src, dst;
    edge_endpoints(ei, e, src, dst);
    atomicAdd(&cnt[dst], 1);
}

__device__ __forceinline__ int block_incl_scan_256(int x, int* wsum) {
    int lane = threadIdx.x & 63, wid = threadIdx.x >> 6;
    #pragma unroll
    for (int off = 1; off < 64; off <<= 1) {
        int y = __shfl_up(x, off, 64);
        if (lane >= off) x += y;
    }
    if (lane == 63) wsum[wid] = x;
    __syncthreads();
    int add = 0;
    #pragma unroll
    for (int w = 0; w < 4; ++w) if (w < wid) add += wsum[w];
    return x + add;
}

__global__ __launch_bounds__(256) void scan1_k(
    const int* __restrict__ cnt, int* __restrict__ rp, int* __restrict__ bsum)
{
    __shared__ int wsum[4];
    int i = blockIdx.x * 256 + threadIdx.x;
    int x = (i < N_NODES) ? cnt[i] : 0;
    int incl = block_incl_scan_256(x, wsum);
    if (i < N_NODES) rp[i] = incl;
    if (threadIdx.x == 255) bsum[blockIdx.x] = incl;
}

__global__ __launch_bounds__(256) void scan2_k(int* __restrict__ bsum)
{
    __shared__ int wsum[4];
    int t = threadIdx.x;
    int x = (t < SCAN_BLOCKS) ? bsum[t] : 0;
    int incl = block_incl_scan_256(x, wsum);
    if (t < SCAN_BLOCKS) bsum[t] = incl - x;   // exclusive
}

__global__ __launch_bounds__(256) void scan3_k(
    const int* __restrict__ cnt, int* __restrict__ rp,
    const int* __restrict__ bsum, int* __restrict__ cursor)
{
    int i = blockIdx.x * 256 + threadIdx.x;
    if (i < N_NODES) {
        int v = rp[i] + bsum[blockIdx.x] - cnt[i];
        rp[i] = v;
        cursor[i] = v;
    }
    if (i == 0) rp[N_NODES] = E_TOT;
}

__global__ __launch_bounds__(256) void csr_scatter_k(
    const int* __restrict__ ei, int* __restrict__ cursor, int* __restrict__ csr_src)
{
    int e = blockIdx.x * 256 + threadIdx.x;
    if (e >= E_TOT) return;
    int src, dst;
    edge_endpoints(ei, e, src, dst);
    int pos = atomicAdd(&cursor[dst], 1);
    csr_src[pos] = src;
}

// ============ fused per-destination GAT aggregation ============
// two-phase softmax: exact per-head max, then branch-free exp+accumulate
// with 4 independent edge streams (slot = t>>5) and float4 gathers.
template<int H, bool RELU>
__global__ __launch_bounds__(128) void gat_fused_k(
    const int* __restrict__ rp, const int* __restrict__ csr_src,
    const float* __restrict__ Hh, const float* __restrict__ sb,
    const float* __restrict__ db, const float* __restrict__ bias,
    float* __restrict__ outv)
{
    constexpr int C = 128 / H;
    const int n = blockIdx.x;
    const int t = threadIdx.x;
    const int beg = rp[n], end = rp[n + 1];

    // destination-side coefficients (uniform per block)
    float dn[H];
    #pragma unroll
    for (int h = 0; h < H; ++h) dn[h] = db[n * H + h];

    // ---- phase 1: exact per-head max over the neighborhood ----
    float mh[H];
    #pragma unroll
    for (int h = 0; h < H; ++h) mh[h] = -3.0e38f;
    for (int i = beg + t; i < end; i += 128) {
        int s = csr_src[i];
        #pragma unroll
        for (int h = 0; h < H; ++h) {
            float v = sb[s * H + h] + dn[h];
            v = v > 0.f ? v : SLOPE * v;
            mh[h] = fmaxf(mh[h], v);
        }
    }
    #pragma unroll
    for (int off = 32; off >= 1; off >>= 1)
        #pragma unroll
        for (int h = 0; h < H; ++h)
            mh[h] = fmaxf(mh[h], __shfl_xor(mh[h], off, 64));
    __shared__ float mred[2][H];
    if ((t & 63) == 0) {
        #pragma unroll
        for (int h = 0; h < H; ++h) mred[t >> 6][h] = mh[h];
    }
    __syncthreads();

    // ---- phase 2: branch-free exp + weighted accumulate ----
    const int slot = t >> 5;          // 4 independent edge streams
    const int q    = t & 31;          // float4 chunk: channels q*4..q*4+3
    const int h    = (q * 4) / C;
    const float m  = fmaxf(mred[0][h], mred[1][h]);
    const float dnh = dn[h];

    const float4* h4 = (const float4*)Hh;
    float4 acc = make_float4(0.f, 0.f, 0.f, 0.f);
    float den = 0.f;
    for (int i = beg + slot; i < end; i += 4) {
        int s = csr_src[i];
        float e = sb[s * H + h] + dnh;
        e = e > 0.f ? e : SLOPE * e;
        float p = __expf(e - m);
        den += p;
        float4 hv = h4[(size_t)s * 32 + q];
        acc.x = fmaf(p, hv.x, acc.x);
        acc.y = fmaf(p, hv.y, acc.y);
        acc.z = fmaf(p, hv.z, acc.z);
        acc.w = fmaf(p, hv.w, acc.w);
    }
    // combine slot pairs within each wave (lanes t and t^32)
    acc.x += __shfl_xor(acc.x, 32, 64);
    acc.y += __shfl_xor(acc.y, 32, 64);
    acc.z += __shfl_xor(acc.z, 32, 64);
    acc.w += __shfl_xor(acc.w, 32, 64);
    den   += __shfl_xor(den,   32, 64);
    // combine the two waves via LDS
    __shared__ float4 sacc[32];
    __shared__ float  sden[32];
    if (t >= 64 && t < 96) { sacc[q] = acc; sden[q] = den; }
    __syncthreads();
    if (t < 32) {
        float4 o = sacc[q];
        float inv = 1.f / (den + sden[q] + EPS_V);
        float4 b4 = ((const float4*)bias)[q];
        float ox = fmaf(acc.x + o.x, inv, 0.f) + b4.x;
        float oy = fmaf(acc.y + o.y, inv, 0.f) + b4.y;
        float oz = fmaf(acc.z + o.z, inv, 0.f) + b4.z;
        float ow = fmaf(acc.w + o.w, inv, 0.f) + b4.w;
        if (RELU) {
            ox = fmaxf(ox, 0.f); oy = fmaxf(oy, 0.f);
            oz = fmaxf(oz, 0.f); ow = fmaxf(ow, 0.f);
        }
        *(float4*)(outv + (size_t)n * 128 + q * 4) = make_float4(ox, oy, oz, ow);
    }
}

template<int H, bool RELU>
void run_layer(const float* xin, const float* Wm, const float* as_, const float* ad_,
               const float* bias, const int* rp, const int* csr_src,
               float* hbuf, float* outv, float* sb, float* db, hipStream_t stream)
{
    gemm128_k<H><<<(N_NODES + 127) / 128, 256, 0, stream>>>(
        xin, Wm, hbuf, N_NODES, as_, ad_, sb, db);
    gat_fused_k<H, RELU><<<N_NODES, 128, 0, stream>>>(rp, csr_src, hbuf, sb, db, bias, outv);
}

} // namespace

extern "C" void kernel_launch(void* const* d_in, const int* in_sizes, int n_in,
                              void* d_out, int out_size, void* d_ws, size_t ws_size,
                              hipStream_t stream)
{
    (void)in_sizes; (void)n_in; (void)out_size; (void)ws_size;
    const float* x   = (const float*)d_in[0];
    const int*   ei  = (const int*)d_in[1];
    const float* W0  = (const float*)d_in[2];
    const float* as0 = (const float*)d_in[3];
    const float* ad0 = (const float*)d_in[4];
    const float* b0  = (const float*)d_in[5];
    const float* W1  = (const float*)d_in[6];
    const float* as1 = (const float*)d_in[7];
    const float* ad1 = (const float*)d_in[8];
    const float* b1  = (const float*)d_in[9];
    const float* W2  = (const float*)d_in[10];
    const float* as2 = (const float*)d_in[11];
    const float* ad2 = (const float*)d_in[12];
    const float* b2  = (const float*)d_in[13];
    float* out = (float*)d_out;

    char* p = (char*)d_ws;
    float* A       = (float*)p;  p += (size_t)N_NODES * 128 * 4;   // h buffer
    float* B       = (float*)p;  p += (size_t)N_NODES * 128 * 4;   // x1 / scratch
    float* sb      = (float*)p;  p += (size_t)N_NODES * 4 * 4;
    float* db      = (float*)p;  p += (size_t)N_NODES * 4 * 4;
    int*   cnt     = (int*)p;    p += (size_t)N_NODES * 4;
    int*   rp      = (int*)p;    p += (size_t)(N_NODES + 1) * 4;
    int*   cursor  = (int*)p;    p += (size_t)N_NODES * 4;
    int*   bsum    = (int*)p;    p += (size_t)SCAN_BLOCKS * 4;
    int*   csr_src = (int*)p;    p += (size_t)E_TOT * 4;

    const int EB = (E_TOT + 255) / 256;

    // ---- CSR build (once; reused by all 3 layers) ----
    hipMemsetAsync(cnt, 0, (size_t)N_NODES * 4, stream);
    csr_count_k<<<EB, 256, 0, stream>>>(ei, cnt);
    scan1_k<<<SCAN_BLOCKS, 256, 0, stream>>>(cnt, rp, bsum);
    scan2_k<<<1, 256, 0, stream>>>(bsum);
    scan3_k<<<SCAN_BLOCKS, 256, 0, stream>>>(cnt, rp, bsum, cursor);
    csr_scatter_k<<<EB, 256, 0, stream>>>(ei, cursor, csr_src);

    // Layer 0: x -> h(A); fused agg -> B (ReLU)
    run_layer<4, true >(x,   W0, as0, ad0, b0, rp, csr_src, A, B,   sb, db, stream);
    // Layer 1: B -> h(A); fused agg -> out (ReLU)
    run_layer<4, true >(B,   W1, as1, ad1, b1, rp, csr_src, A, out, sb, db, stream);
    // Layer 2 (H=1): out -> h(A); fused agg -> out (no ReLU)
    run_layer<1, false>(out, W2, as2, ad2, b2, rp, csr_src, A, out, sb, db, stream);
}